// Round 1
// baseline (460.494 us; speedup 1.0000x reference)
//
#include <hip/hip_runtime.h>
#include <math.h>

#define IMG_H 8192
#define IMG_W 8192
#define ROWS_PER_THREAD 16

typedef float vfloat4 __attribute__((ext_vector_type(4)));

// Block = (64,4): one wave per threadIdx.y. Each thread: 4 cols x 16 rows.
// Block tile: 256 px wide x 64 rows. Grid = (32, 128).
__global__ __launch_bounds__(256) void repair_kernel(const float* __restrict__ img,
                                                     float* __restrict__ out) {
    const int bx = blockIdx.x;
    const int lane = threadIdx.x;                    // 0..63 == full wave
    const int x4 = bx * 256 + lane * 4;
    const int y0 = (blockIdx.y * blockDim.y + threadIdx.y) * ROWS_PER_THREAD;
    const bool x_edge_blk = (bx == 0) || (bx == (int)gridDim.x - 1);

    const float inv9 = 1.0f / 9.0f;

    float w[3][6];   // rolling 3-row window: [left, c.x, c.y, c.z, c.w, right]

    auto load_row = [&](int yy, float* row) {
        if (yy >= 0 && yy < IMG_H) {                 // wave-uniform condition
            const float* rp = img + (size_t)yy * IMG_W + x4;
            const float4 c = *(const float4*)rp;
            float lw = __shfl_up(c.w, 1);            // lane i-1's last element
            float rw = __shfl_down(c.x, 1);          // lane i+1's first element
            if (lane == 0)  lw = (x4 > 0)         ? rp[-1] : 0.0f;
            if (lane == 63) rw = (x4 + 4 < IMG_W) ? rp[4]  : 0.0f;
            row[0] = lw; row[1] = c.x; row[2] = c.y; row[3] = c.z; row[4] = c.w; row[5] = rw;
        } else {
            row[0] = row[1] = row[2] = row[3] = row[4] = row[5] = 0.0f;
        }
    };

    load_row(y0 - 1, w[0]);
    load_row(y0,     w[1]);

    #pragma unroll
    for (int r = 0; r < ROWS_PER_THREAD; ++r) {
        load_row(y0 + r + 1, w[(r + 2) % 3]);
        const float* up  = w[r % 3];
        const float* mid = w[(r + 1) % 3];
        const float* dn  = w[(r + 2) % 3];
        const int y = y0 + r;

        float res[4];
        #pragma unroll
        for (int j = 0; j < 4; ++j) {
            // 3x3 box mean, exact reference op order (row-major taps, no fma)
            float acc = 0.0f;
            #pragma unroll
            for (int cc = 0; cc < 3; ++cc) acc = __fadd_rn(acc, __fmul_rn(up[j + cc],  inv9));
            #pragma unroll
            for (int cc = 0; cc < 3; ++cc) acc = __fadd_rn(acc, __fmul_rn(mid[j + cc], inv9));
            #pragma unroll
            for (int cc = 0; cc < 3; ++cc) acc = __fadd_rn(acc, __fmul_rn(dn[j + cc],  inv9));

            const float x = mid[j + 1];
            // interior: coeff==1.0 (bitwise identity), cnt==4 (x*0.25 == x/4 exactly)
            const bool mask = (x > __fmul_rn(5.0f, acc)) || (x > 1000.0f);
            const float nsum = __fadd_rn(
                __fadd_rn(__fadd_rn(up[j + 1], dn[j + 1]), mid[j]), mid[j + 2]);
            const float rep = floorf(__fmul_rn(nsum, 0.25f));
            res[j] = mask ? rep : x;
        }

        const bool row_edge = (y == 0) || (y == IMG_H - 1);
        if (x_edge_blk || row_edge) {                // wave-uniform, rare
            const float cnt_row = (float)((y > 0) + (y < IMG_H - 1));
            #pragma unroll
            for (int j = 0; j < 4; ++j) {
                const int gx = x4 + j;
                const bool col_edge = (gx == 0) || (gx == IMG_W - 1);
                if (col_edge || row_edge) {
                    float acc = 0.0f;
                    #pragma unroll
                    for (int cc = 0; cc < 3; ++cc) acc = __fadd_rn(acc, __fmul_rn(up[j + cc],  inv9));
                    #pragma unroll
                    for (int cc = 0; cc < 3; ++cc) acc = __fadd_rn(acc, __fmul_rn(mid[j + cc], inv9));
                    #pragma unroll
                    for (int cc = 0; cc < 3; ++cc) acc = __fadd_rn(acc, __fmul_rn(dn[j + cc],  inv9));

                    const float coeff = (row_edge && col_edge) ? 2.25f : 1.5f;
                    const float img_mean = __fmul_rn(acc, coeff);
                    const float x = mid[j + 1];
                    const bool mask = (x > __fmul_rn(5.0f, img_mean)) || (x > 1000.0f);
                    const float nsum = __fadd_rn(
                        __fadd_rn(__fadd_rn(up[j + 1], dn[j + 1]), mid[j]), mid[j + 2]);
                    const float cnt = cnt_row + (float)((gx > 0) + (gx < IMG_W - 1));
                    const float rep = floorf(__fdiv_rn(nsum, cnt));
                    res[j] = mask ? rep : x;
                }
            }
        }

        vfloat4 o;
        o.x = res[0]; o.y = res[1]; o.z = res[2]; o.w = res[3];
        __builtin_nontemporal_store(o, (vfloat4*)(out + (size_t)y * IMG_W + x4));
    }
}

extern "C" void kernel_launch(void* const* d_in, const int* in_sizes, int n_in,
                              void* d_out, int out_size, void* d_ws, size_t ws_size,
                              hipStream_t stream) {
    const float* img = (const float*)d_in[0];
    float* out = (float*)d_out;

    dim3 block(64, 4);
    dim3 grid(IMG_W / 256, IMG_H / (4 * ROWS_PER_THREAD));   // (32, 128)
    repair_kernel<<<grid, block, 0, stream>>>(img, out);
}

// Round 3
// 451.867 us; speedup vs baseline: 1.0191x; 1.0191x over previous
//
#include <hip/hip_runtime.h>
#include <math.h>

#define IMG_H 8192
#define IMG_W 8192
#define ROWS_PER_THREAD 16
#define PF 4   // raw-row register FIFO slots (prefetch distance 3 rows)

typedef float vfloat4 __attribute__((ext_vector_type(4)));

struct RawRow { float4 c; float edge; };  // edge: lane0 keeps left halo, lane63 right halo

// Block = (64,4): one wave per threadIdx.y. Each thread: 4 cols x 16 rows.
// Block tile: 256 px wide x 64 rows. Grid = (32, 128).
__global__ __launch_bounds__(256) void repair_kernel(const float* __restrict__ img,
                                                     float* __restrict__ out) {
    const int bx = blockIdx.x;
    const int lane = threadIdx.x;                    // 0..63 == full wave
    const int x4 = bx * 256 + lane * 4;
    const int y0 = (blockIdx.y * blockDim.y + threadIdx.y) * ROWS_PER_THREAD;
    const bool x_edge_blk = (bx == 0) || (bx == (int)gridDim.x - 1);

    const float inv9 = 1.0f / 9.0f;

    RawRow fifo[PF];   // slot for row-index i is fifo[i % PF]
    float w[3][6];     // expanded 3-row window: [left, c.x, c.y, c.z, c.w, right]

    // i is the strip-relative row index: global row = y0 - 1 + i, i in [0, 17]
    auto load_raw = [&](int i, RawRow& s) {
        const int yy = y0 - 1 + i;
        if (yy >= 0 && yy < IMG_H) {                 // wave-uniform condition
            const float* rp = img + (size_t)yy * IMG_W + x4;
            s.c = *(const float4*)rp;
            float e = 0.0f;
            if (lane == 0 && x4 > 0)           e = rp[-1];
            if (lane == 63 && x4 + 4 < IMG_W)  e = rp[4];
            s.edge = e;
        } else {
            s.c.x = 0.0f; s.c.y = 0.0f; s.c.z = 0.0f; s.c.w = 0.0f;
            s.edge = 0.0f;
        }
    };

    // Expansion (shfl + halo merge) deferred to CONSUME time so the vmcnt wait
    // lands 3 iterations after the load was issued.
    auto expand = [&](const RawRow& s, float* row) {
        float lw = __shfl_up(s.c.w, 1);              // lane i-1's last element
        float rw = __shfl_down(s.c.x, 1);            // lane i+1's first element
        if (lane == 0)  lw = s.edge;
        if (lane == 63) rw = s.edge;
        row[0] = lw; row[1] = s.c.x; row[2] = s.c.y; row[3] = s.c.z; row[4] = s.c.w; row[5] = rw;
    };

    // Prologue: fill the pipeline with rows i = 0..4.
    load_raw(0, fifo[0]);
    load_raw(1, fifo[1]);
    load_raw(2, fifo[2]);
    load_raw(3, fifo[3]);
    expand(fifo[0], w[0]);     // row i=0 -> "up" of r=0   (frees slot 0)
    expand(fifo[1], w[1]);     // row i=1 -> "mid" of r=0  (frees slot 1)
    load_raw(4, fifo[0]);      // i=4 into slot 4%4 = 0

    #pragma unroll
    for (int r = 0; r < ROWS_PER_THREAD; ++r) {
        // Prefetch row i = r+5 into the slot of i = r+1 (already expanded).
        if (r + 5 <= ROWS_PER_THREAD + 1)
            load_raw(r + 5, fifo[(r + 1) % PF]);

        // Consume row i = r+2 (its load was issued 3 iterations ago).
        expand(fifo[(r + 2) % PF], w[(r + 2) % 3]);

        const float* up  = w[r % 3];
        const float* mid = w[(r + 1) % 3];
        const float* dn  = w[(r + 2) % 3];
        const int y = y0 + r;

        float res[4];
        #pragma unroll
        for (int j = 0; j < 4; ++j) {
            // 3x3 box mean, exact reference op order (row-major taps, no fma)
            float acc = 0.0f;
            #pragma unroll
            for (int cc = 0; cc < 3; ++cc) acc = __fadd_rn(acc, __fmul_rn(up[j + cc],  inv9));
            #pragma unroll
            for (int cc = 0; cc < 3; ++cc) acc = __fadd_rn(acc, __fmul_rn(mid[j + cc], inv9));
            #pragma unroll
            for (int cc = 0; cc < 3; ++cc) acc = __fadd_rn(acc, __fmul_rn(dn[j + cc],  inv9));

            const float x = mid[j + 1];
            // interior: coeff==1.0 (bitwise identity), cnt==4 (x*0.25 == x/4 exactly)
            const bool mask = (x > __fmul_rn(5.0f, acc)) || (x > 1000.0f);
            const float nsum = __fadd_rn(
                __fadd_rn(__fadd_rn(up[j + 1], dn[j + 1]), mid[j]), mid[j + 2]);
            const float rep = floorf(__fmul_rn(nsum, 0.25f));
            res[j] = mask ? rep : x;
        }

        const bool row_edge = (y == 0) || (y == IMG_H - 1);
        if (x_edge_blk || row_edge) {                // wave-uniform, rare
            const float cnt_row = (float)((y > 0) + (y < IMG_H - 1));
            #pragma unroll
            for (int j = 0; j < 4; ++j) {
                const int gx = x4 + j;
                const bool col_edge = (gx == 0) || (gx == IMG_W - 1);
                if (col_edge || row_edge) {
                    float acc = 0.0f;
                    #pragma unroll
                    for (int cc = 0; cc < 3; ++cc) acc = __fadd_rn(acc, __fmul_rn(up[j + cc],  inv9));
                    #pragma unroll
                    for (int cc = 0; cc < 3; ++cc) acc = __fadd_rn(acc, __fmul_rn(mid[j + cc], inv9));
                    #pragma unroll
                    for (int cc = 0; cc < 3; ++cc) acc = __fadd_rn(acc, __fmul_rn(dn[j + cc],  inv9));

                    const float coeff = (row_edge && col_edge) ? 2.25f : 1.5f;
                    const float img_mean = __fmul_rn(acc, coeff);
                    const float x = mid[j + 1];
                    const bool mask = (x > __fmul_rn(5.0f, img_mean)) || (x > 1000.0f);
                    const float nsum = __fadd_rn(
                        __fadd_rn(__fadd_rn(up[j + 1], dn[j + 1]), mid[j]), mid[j + 2]);
                    const float cnt = cnt_row + (float)((gx > 0) + (gx < IMG_W - 1));
                    const float rep = floorf(__fdiv_rn(nsum, cnt));
                    res[j] = mask ? rep : x;
                }
            }
        }

        vfloat4 o;
        o.x = res[0]; o.y = res[1]; o.z = res[2]; o.w = res[3];
        __builtin_nontemporal_store(o, (vfloat4*)(out + (size_t)y * IMG_W + x4));
    }
}

extern "C" void kernel_launch(void* const* d_in, const int* in_sizes, int n_in,
                              void* d_out, int out_size, void* d_ws, size_t ws_size,
                              hipStream_t stream) {
    const float* img = (const float*)d_in[0];
    float* out = (float*)d_out;

    dim3 block(64, 4);
    dim3 grid(IMG_W / 256, IMG_H / (4 * ROWS_PER_THREAD));   // (32, 128)
    repair_kernel<<<grid, block, 0, stream>>>(img, out);
}